// Round 11
// baseline (296.620 us; speedup 1.0000x reference)
//
#include <hip/hip_runtime.h>
#include <math.h>

#define NP 48   // 16 batch * 3 channels

typedef float v2f __attribute__((ext_vector_type(2)));

__device__ __forceinline__ float uniform_f(float v) {
    int i = __builtin_amdgcn_readfirstlane(__builtin_bit_cast(int, v));
    return __builtin_bit_cast(float, i);
}

// ---------------- chunked sliding-window SSIM core (R10 core, variable BH, wave-local reduce) ----------------
__device__ __forceinline__ void ssim_scale(
        const float* __restrict__ P, const float* __restrict__ T,
        int H, int sh, int lb, int scale, int bslot, int tid,
        const float* __restrict__ k2d, double* __restrict__ accum,
        int BH, int nch)
{
    // normalized 1D gaussian from center row of 2D kernel, pinned to SGPRs
    float w[11];
    {
        float s = 0.f;
#pragma unroll
        for (int i = 0; i < 11; ++i) s += k2d[55 + i];
        float inv = 1.0f / s;
#pragma unroll
        for (int i = 0; i < 11; ++i) w[i] = uniform_f(k2d[55 + i] * inv);
    }

    int blocksX = (NP << sh) >> 8;          // 48*H / 256
    int bxi = lb % blocksX;
    int by  = lb / blocksX;
    int g   = (bxi << 8) + tid;
    int pl  = g >> sh;
    int x   = g & (H - 1);
    int yb  = by * BH;
    int yend = yb + BH;

    // per-lane clamped window base + edge-zeroed weights (unified load path)
    int bcl = x - 5;
    bcl = bcl < 0 ? 0 : bcl;
    bcl = bcl > H - 11 ? H - 11 : bcl;
    int d = bcl - (x - 5);                  // in [-5, 5]; 0 interior
    float wc[11];
#pragma unroll
    for (int j = 0; j < 11; ++j) {
        int idx = j + d;
        float val = 0.f;
#pragma unroll
        for (int i = 0; i < 11; ++i) val = (idx == i) ? w[i] : val;
        wc[j] = val;
    }

    const float* pP = P + (size_t)pl * H * H + (ptrdiff_t)(yb - 5) * H + bcl;
    const float* pT = T + (size_t)pl * H * H + (ptrdiff_t)(yb - 5) * H + bcl;

    v2f wmu[11], we[11];
    float wpt[11];
    const float C1 = 1e-4f, C2 = 9e-4f;
    float lsum = 0.f, csum = 0.f;
    int rr = yb - 5;

    for (int ch = 0; ch < nch; ++ch) {      // nch*11 slots >= BH+10 steps
#pragma unroll
        for (int ph = 0; ph < 11; ++ph) {
            bool live = rr < yend + 5;      // uniform
            v2f a_mu = (v2f){0.f, 0.f};
            v2f a_e  = (v2f){0.f, 0.f};
            v2f a_pt = (v2f){0.f, 0.f};
            if (live && rr >= 0 && rr < H) {   // uniform row guard
#pragma unroll
                for (int j = 0; j < 11; ++j) {
                    v2f pt2 = (v2f){pP[j], pT[j]};
                    v2f wv  = (v2f){wc[j], wc[j]};
                    v2f wp2 = wv * pt2;
                    v2f ptr2 = (v2f){pt2.y, pt2.x};
                    a_mu += wp2;
                    a_e  += wp2 * pt2;
                    a_pt += wp2 * ptr2;        // halves: wp*t , wt*p
                }
            }
            wmu[ph] = a_mu; we[ph] = a_e;
            wpt[ph] = a_pt.x + a_pt.y;         // = 2*sum(w p t)
            if (live && rr >= yb + 5) {        // emit output row rr-5
                v2f mu2 = (v2f){0.f, 0.f};
                v2f e2  = (v2f){0.f, 0.f};
                float ept = 0.f;
#pragma unroll
                for (int i = 0; i < 11; ++i) {
                    const int sl = (ph + 1 + i) % 11;   // compile-time
                    v2f wi = (v2f){w[i], w[i]};         // SGPR broadcast
                    mu2 += wi * wmu[sl];
                    e2  += wi * we[sl];
                    ept += w[i] * wpt[sl];
                }
                float m11 = mu2.x * mu2.x, m22 = mu2.y * mu2.y, m12 = mu2.x * mu2.y;
                float s1  = fmaxf(e2.x - m11, 0.f);
                float s2  = fmaxf(e2.y - m22, 0.f);
                float s12 = 0.5f * ept - m12;
                lsum += (2.f * m12 + C1) * __builtin_amdgcn_rcpf(m11 + m22 + C1);
                csum += (2.f * s12 + C2) * __builtin_amdgcn_rcpf(s1 + s2 + C2);
            }
            rr++; pP += H; pT += H;
        }
    }

    // wave-local shuffle reduce, one atomic pair per wave (no barrier, no LDS)
#pragma unroll
    for (int o = 32; o > 0; o >>= 1) {
        lsum += __shfl_down(lsum, o, 64);
        csum += __shfl_down(csum, o, 64);
    }
    if ((tid & 63) == 0) {
        int slot = (scale * 8 + ((bslot + (tid >> 6)) & 7)) * 2;
        atomicAdd(&accum[slot],     (double)lsum);
        atomicAdd(&accum[slot + 1], (double)csum);
    }
}

// ---------------- kernel A: ssim scale-0 blocks [0,768) || pool blocks [768,2304) ----------------
__global__ __launch_bounds__(256) void k_main(
        const float* __restrict__ pred, const float* __restrict__ targ,
        float* __restrict__ p1, float* __restrict__ t1,
        float* __restrict__ p2, float* __restrict__ t2,
        float* __restrict__ p3, float* __restrict__ t3,
        float* __restrict__ p4, float* __restrict__ t4,
        const float* __restrict__ k2d, double* __restrict__ accum) {
    int b   = blockIdx.x;
    int tid = threadIdx.x;
    if (b < 768) {   // scale 0, BH=64 (long blocks dispatched first)
        ssim_scale(pred, targ, 512, 9, b, 0, b, tid, k2d, accum, 64, 7);
        return;
    }
    // ---- pool path: 64x64 s1 tile; all scales from s0 (mean of means) ----
    int pb   = b - 768;
    int pi   = pb >> 4;          // 0..95 plane-image
    int tile = pb & 15;          // 4x4 tiles over the 256x256 s1 plane
    int pls  = pi < 48 ? pi : pi - 48;
    const float* src = (pi < 48 ? pred : targ) + (size_t)pls * 512 * 512;
    float* d1 = (pi < 48 ? p1 : t1) + (size_t)pls * 256 * 256;
    float* d2 = (pi < 48 ? p2 : t2) + (size_t)pls * 128 * 128;
    float* d3 = (pi < 48 ? p3 : t3) + (size_t)pls * 64 * 64;
    float* d4 = (pi < 48 ? p4 : t4) + (size_t)pls * 32 * 32;
    int tY = tile >> 2, tX = tile & 3;
    int ty = tid >> 4, tx = tid & 15;
    int gy0 = tY * 128 + ty * 8, gx0 = tX * 128 + tx * 8;

    float s1v[4][4];
#pragma unroll
    for (int i = 0; i < 4; ++i) {
        const float* r0 = src + (size_t)(gy0 + 2 * i) * 512 + gx0;
        const float* r1 = r0 + 512;
        float4 a0 = *(const float4*)r0, a1 = *(const float4*)(r0 + 4);
        float4 b0 = *(const float4*)r1, b1 = *(const float4*)(r1 + 4);
        s1v[i][0] = 0.25f * ((a0.x + a0.y) + (b0.x + b0.y));
        s1v[i][1] = 0.25f * ((a0.z + a0.w) + (b0.z + b0.w));
        s1v[i][2] = 0.25f * ((a1.x + a1.y) + (b1.x + b1.y));
        s1v[i][3] = 0.25f * ((a1.z + a1.w) + (b1.z + b1.w));
        *(float4*)(d1 + (size_t)(tY * 64 + ty * 4 + i) * 256 + tX * 64 + tx * 4) =
            *(float4*)s1v[i];
    }
    float s2v[2][2];
#pragma unroll
    for (int i = 0; i < 2; ++i) {
#pragma unroll
        for (int j = 0; j < 2; ++j)
            s2v[i][j] = 0.25f * ((s1v[2*i][2*j] + s1v[2*i][2*j+1]) +
                                 (s1v[2*i+1][2*j] + s1v[2*i+1][2*j+1]));
        *(float2*)(d2 + (size_t)(tY * 32 + ty * 2 + i) * 128 + tX * 32 + tx * 2) =
            *(float2*)s2v[i];
    }
    float s3 = 0.25f * ((s2v[0][0] + s2v[0][1]) + (s2v[1][0] + s2v[1][1]));
    d3[(size_t)(tY * 16 + ty) * 64 + tX * 16 + tx] = s3;
    float v1 = s3 + __shfl_xor(s3, 1, 64);
    float v2 = v1 + __shfl_xor(v1, 16, 64);
    if ((ty & 1) == 0 && (tx & 1) == 0)
        d4[(size_t)(tY * 8 + (ty >> 1)) * 32 + tX * 8 + (tx >> 1)] = 0.25f * v2;
}

// ---------------- kernel B: ssim scales 1-4; last wave finalizes ----------------
// Blocks: [0,192) s1(BH=64)  [192,288) s2(BH=32)  [288,312) s3  [312,318) s4
// Total waves = 318*4 = 1272.
__global__ __launch_bounds__(256) void k_ssim_rest(
        const float* __restrict__ p1, const float* __restrict__ t1,
        const float* __restrict__ p2, const float* __restrict__ t2,
        const float* __restrict__ p3, const float* __restrict__ t3,
        const float* __restrict__ p4, const float* __restrict__ t4,
        const float* __restrict__ k2d, double* __restrict__ accum,
        unsigned* __restrict__ done, float* __restrict__ out) {
    int b   = blockIdx.x;
    int tid = threadIdx.x;
    if (b < 192)      ssim_scale(p1, t1, 256, 8, b,       1, b, tid, k2d, accum, 64, 7);
    else if (b < 288) ssim_scale(p2, t2, 128, 7, b - 192, 2, b, tid, k2d, accum, 32, 4);
    else if (b < 312) ssim_scale(p3, t3, 64,  6, b - 288, 3, b, tid, k2d, accum, 32, 4);
    else              ssim_scale(p4, t4, 32,  5, b - 312, 4, b, tid, k2d, accum, 32, 4);

    if ((tid & 63) == 0) {
        __threadfence();                    // release: accum atomics visible
        unsigned old = atomicAdd(done, 1u);
        if (old == 1271u) {                 // last wave finalizes
            __threadfence();                // acquire
            const float wts[5] = {0.0448f, 0.2856f, 0.3001f, 0.2363f, 0.1333f};
            float ms = 1.0f;
            int Hs = 512;
            for (int s = 0; s < 5; ++s) {
                double lt = 0.0, ct = 0.0;
                for (int k = 0; k < 8; ++k) {
                    lt += atomicAdd(&accum[(s * 8 + k) * 2],     0.0);
                    ct += atomicAdd(&accum[(s * 8 + k) * 2 + 1], 0.0);
                }
                float N  = 48.0f * (float)Hs * (float)Hs;
                float l  = (float)lt / N;
                float cs = fmaxf((float)ct / N, 1e-8f);
                if (s == 4) {
                    l = fmaxf(l, 1e-8f);
                    ms *= powf(l, wts[s]) * powf(cs, wts[s]);
                } else {
                    ms *= powf(cs, wts[s]);
                }
                Hs >>= 1;
            }
            out[0] = ms;
        }
    }
}

extern "C" void kernel_launch(void* const* d_in, const int* in_sizes, int n_in,
                              void* d_out, int out_size, void* d_ws, size_t ws_size,
                              hipStream_t stream) {
    const float* pred = (const float*)d_in[0];
    const float* targ = (const float*)d_in[1];
    const float* kern = (const float*)d_in[2];
    float* out = (float*)d_out;

    char* ws = (char*)d_ws;
    double*   accum = (double*)ws;           // 80 doubles (5 scales * 8 slots * 2)
    unsigned* done  = (unsigned*)(ws + 768);
    size_t off = 1024;
    float* p1 = (float*)(ws + off); off += (size_t)NP * 256 * 256 * 4;
    float* t1 = (float*)(ws + off); off += (size_t)NP * 256 * 256 * 4;
    float* p2 = (float*)(ws + off); off += (size_t)NP * 128 * 128 * 4;
    float* t2 = (float*)(ws + off); off += (size_t)NP * 128 * 128 * 4;
    float* p3 = (float*)(ws + off); off += (size_t)NP * 64 * 64 * 4;
    float* t3 = (float*)(ws + off); off += (size_t)NP * 64 * 64 * 4;
    float* p4 = (float*)(ws + off); off += (size_t)NP * 32 * 32 * 4;
    float* t4 = (float*)(ws + off); off += (size_t)NP * 32 * 32 * 4;

    hipMemsetAsync(ws, 0, 1024, stream);     // zero accum + done
    k_main<<<2304, 256, 0, stream>>>(pred, targ, p1, t1, p2, t2, p3, t3, p4, t4, kern, accum);
    k_ssim_rest<<<318, 256, 0, stream>>>(p1, t1, p2, t2, p3, t3, p4, t4, kern, accum, done, out);
}

// Round 12
// 237.322 us; speedup vs baseline: 1.2499x; 1.2499x over previous
//
#include <hip/hip_runtime.h>
#include <math.h>

#define NP 48   // 16 batch * 3 channels

typedef float v2f __attribute__((ext_vector_type(2)));

__device__ __forceinline__ float uniform_f(float v) {
    int i = __builtin_amdgcn_readfirstlane(__builtin_bit_cast(int, v));
    return __builtin_bit_cast(float, i);
}

// ---------------- chunked sliding-window SSIM core (R6 loop shape + R8 math) ----------------
__device__ __forceinline__ void ssim_scale(
        const float* __restrict__ P, const float* __restrict__ T,
        int H, int sh, int lb, int scale, int slotsel, int tid,
        const float* __restrict__ k2d, double* __restrict__ accum)
{
    // normalized 1D gaussian from center row of 2D kernel, pinned to SGPRs
    float w[11];
    {
        float s = 0.f;
#pragma unroll
        for (int i = 0; i < 11; ++i) s += k2d[55 + i];
        float inv = 1.0f / s;
#pragma unroll
        for (int i = 0; i < 11; ++i) w[i] = uniform_f(k2d[55 + i] * inv);
    }

    int blocksX = (NP << sh) >> 8;          // 48*H / 256
    int bxi = lb % blocksX;
    int by  = lb / blocksX;
    int g   = (bxi << 8) + tid;
    int pl  = g >> sh;
    int x   = g & (H - 1);
    int yb  = by * 32;
    int yend = yb + 32;

    // per-lane clamped window base + edge-zeroed weights (unified load path)
    int bcl = x - 5;
    bcl = bcl < 0 ? 0 : bcl;
    bcl = bcl > H - 11 ? H - 11 : bcl;
    int d = bcl - (x - 5);                  // in [-5, 5]; 0 interior
    float wc[11];
#pragma unroll
    for (int j = 0; j < 11; ++j) {
        int idx = j + d;
        float val = 0.f;
#pragma unroll
        for (int i = 0; i < 11; ++i) val = (idx == i) ? w[i] : val;
        wc[j] = val;
    }

    const float* pP = P + (size_t)pl * H * H + (ptrdiff_t)(yb - 5) * H + bcl;
    const float* pT = T + (size_t)pl * H * H + (ptrdiff_t)(yb - 5) * H + bcl;

    v2f wmu[11], we[11];
    float wpt[11];
    const float C1 = 1e-4f, C2 = 9e-4f;
    float lsum = 0.f, csum = 0.f;
    int rr = yb - 5;

    for (int ch = 0; ch < 4; ++ch) {        // 4*11 = 44 slots >= 42 steps
#pragma unroll
        for (int ph = 0; ph < 11; ++ph) {
            bool live = rr < yend + 5;      // uniform
            v2f a_mu = (v2f){0.f, 0.f};
            v2f a_e  = (v2f){0.f, 0.f};
            v2f a_pt = (v2f){0.f, 0.f};
            if (live && rr >= 0 && rr < H) {   // uniform row guard
#pragma unroll
                for (int j = 0; j < 11; ++j) {
                    v2f pt2 = (v2f){pP[j], pT[j]};
                    v2f wv  = (v2f){wc[j], wc[j]};
                    v2f wp2 = wv * pt2;
                    v2f ptr2 = (v2f){pt2.y, pt2.x};
                    a_mu += wp2;
                    a_e  += wp2 * pt2;
                    a_pt += wp2 * ptr2;        // halves: wp*t , wt*p
                }
            }
            wmu[ph] = a_mu; we[ph] = a_e;
            wpt[ph] = a_pt.x + a_pt.y;         // = 2*sum(w p t)
            if (live && rr >= yb + 5) {        // emit output row rr-5
                v2f mu2 = (v2f){0.f, 0.f};
                v2f e2  = (v2f){0.f, 0.f};
                float ept = 0.f;
#pragma unroll
                for (int i = 0; i < 11; ++i) {
                    const int sl = (ph + 1 + i) % 11;   // compile-time
                    v2f wi = (v2f){w[i], w[i]};         // SGPR broadcast
                    mu2 += wi * wmu[sl];
                    e2  += wi * we[sl];
                    ept += w[i] * wpt[sl];
                }
                float m11 = mu2.x * mu2.x, m22 = mu2.y * mu2.y, m12 = mu2.x * mu2.y;
                float s1  = fmaxf(e2.x - m11, 0.f);
                float s2  = fmaxf(e2.y - m22, 0.f);
                float s12 = 0.5f * ept - m12;
                lsum += (2.f * m12 + C1) * __builtin_amdgcn_rcpf(m11 + m22 + C1);
                csum += (2.f * s12 + C2) * __builtin_amdgcn_rcpf(s1 + s2 + C2);
            }
            rr++; pP += H; pT += H;
        }
    }

    // wave shuffle reduce then cross-wave via LDS
#pragma unroll
    for (int o = 32; o > 0; o >>= 1) {
        lsum += __shfl_down(lsum, o, 64);
        csum += __shfl_down(csum, o, 64);
    }
    __shared__ float red[8];
    int wv = tid >> 6;
    if ((tid & 63) == 0) { red[2 * wv] = lsum; red[2 * wv + 1] = csum; }
    __syncthreads();
    if (tid == 0) {
        int slot = (scale * 8 + slotsel) * 2;
        atomicAdd(&accum[slot],     (double)(red[0] + red[2] + red[4] + red[6]));
        atomicAdd(&accum[slot + 1], (double)(red[1] + red[3] + red[5] + red[7]));
    }
}

// ---------------- kernel A: pool blocks [0,1536) || ssim scale-0 blocks [1536,3072) ----------------
__global__ __launch_bounds__(256) void k_main(
        const float* __restrict__ pred, const float* __restrict__ targ,
        float* __restrict__ p1, float* __restrict__ t1,
        float* __restrict__ p2, float* __restrict__ t2,
        float* __restrict__ p3, float* __restrict__ t3,
        float* __restrict__ p4, float* __restrict__ t4,
        const float* __restrict__ k2d, double* __restrict__ accum) {
    int b   = blockIdx.x;
    int tid = threadIdx.x;
    if (b >= 1536) {
        ssim_scale(pred, targ, 512, 9, b - 1536, 0, b & 7, tid, k2d, accum);
        return;
    }
    // ---- pool path: 64x64 s1 tile; all scales from s0 (mean of means) ----
    int pi   = b >> 4;          // 0..95 plane-image
    int tile = b & 15;          // 4x4 tiles over the 256x256 s1 plane
    int pls  = pi < 48 ? pi : pi - 48;
    const float* src = (pi < 48 ? pred : targ) + (size_t)pls * 512 * 512;
    float* d1 = (pi < 48 ? p1 : t1) + (size_t)pls * 256 * 256;
    float* d2 = (pi < 48 ? p2 : t2) + (size_t)pls * 128 * 128;
    float* d3 = (pi < 48 ? p3 : t3) + (size_t)pls * 64 * 64;
    float* d4 = (pi < 48 ? p4 : t4) + (size_t)pls * 32 * 32;
    int tY = tile >> 2, tX = tile & 3;
    int ty = tid >> 4, tx = tid & 15;
    int gy0 = tY * 128 + ty * 8, gx0 = tX * 128 + tx * 8;

    float s1v[4][4];
#pragma unroll
    for (int i = 0; i < 4; ++i) {
        const float* r0 = src + (size_t)(gy0 + 2 * i) * 512 + gx0;
        const float* r1 = r0 + 512;
        float4 a0 = *(const float4*)r0, a1 = *(const float4*)(r0 + 4);
        float4 b0 = *(const float4*)r1, b1 = *(const float4*)(r1 + 4);
        s1v[i][0] = 0.25f * ((a0.x + a0.y) + (b0.x + b0.y));
        s1v[i][1] = 0.25f * ((a0.z + a0.w) + (b0.z + b0.w));
        s1v[i][2] = 0.25f * ((a1.x + a1.y) + (b1.x + b1.y));
        s1v[i][3] = 0.25f * ((a1.z + a1.w) + (b1.z + b1.w));
        *(float4*)(d1 + (size_t)(tY * 64 + ty * 4 + i) * 256 + tX * 64 + tx * 4) =
            *(float4*)s1v[i];
    }
    float s2v[2][2];
#pragma unroll
    for (int i = 0; i < 2; ++i) {
#pragma unroll
        for (int j = 0; j < 2; ++j)
            s2v[i][j] = 0.25f * ((s1v[2*i][2*j] + s1v[2*i][2*j+1]) +
                                 (s1v[2*i+1][2*j] + s1v[2*i+1][2*j+1]));
        *(float2*)(d2 + (size_t)(tY * 32 + ty * 2 + i) * 128 + tX * 32 + tx * 2) =
            *(float2*)s2v[i];
    }
    float s3 = 0.25f * ((s2v[0][0] + s2v[0][1]) + (s2v[1][0] + s2v[1][1]));
    d3[(size_t)(tY * 16 + ty) * 64 + tX * 16 + tx] = s3;
    float v1 = s3 + __shfl_xor(s3, 1, 64);
    float v2 = v1 + __shfl_xor(v1, 16, 64);
    if ((ty & 1) == 0 && (tx & 1) == 0)
        d4[(size_t)(tY * 8 + (ty >> 1)) * 32 + tX * 8 + (tx >> 1)] = 0.25f * v2;
}

// ---------------- kernel B: ssim scales 1-4 (depend on pools) ----------------
__global__ __launch_bounds__(256) void k_ssim_rest(
        const float* __restrict__ p1, const float* __restrict__ t1,
        const float* __restrict__ p2, const float* __restrict__ t2,
        const float* __restrict__ p3, const float* __restrict__ t3,
        const float* __restrict__ p4, const float* __restrict__ t4,
        const float* __restrict__ k2d, double* __restrict__ accum) {
    int b   = blockIdx.x;
    int tid = threadIdx.x;
    if (b < 384)      ssim_scale(p1, t1, 256, 8, b,       1, b & 7, tid, k2d, accum);
    else if (b < 480) ssim_scale(p2, t2, 128, 7, b - 384, 2, b & 7, tid, k2d, accum);
    else if (b < 504) ssim_scale(p3, t3, 64,  6, b - 480, 3, b & 7, tid, k2d, accum);
    else              ssim_scale(p4, t4, 32,  5, b - 504, 4, b & 7, tid, k2d, accum);
}

// ---------------- finalize: weighted power product ----------------
__global__ void k_final(const double* __restrict__ accum, float* __restrict__ out) {
    if (threadIdx.x != 0 || blockIdx.x != 0) return;
    const float wts[5] = {0.0448f, 0.2856f, 0.3001f, 0.2363f, 0.1333f};
    float ms = 1.0f;
    int Hs = 512;
    for (int s = 0; s < 5; ++s) {
        double lt = 0.0, ct = 0.0;
        for (int k = 0; k < 8; ++k) {
            lt += accum[(s * 8 + k) * 2];
            ct += accum[(s * 8 + k) * 2 + 1];
        }
        float N  = 48.0f * (float)Hs * (float)Hs;
        float l  = (float)lt / N;
        float cs = fmaxf((float)ct / N, 1e-8f);
        if (s == 4) {
            l = fmaxf(l, 1e-8f);
            ms *= powf(l, wts[s]) * powf(cs, wts[s]);
        } else {
            ms *= powf(cs, wts[s]);
        }
        Hs >>= 1;
    }
    out[0] = ms;
}

extern "C" void kernel_launch(void* const* d_in, const int* in_sizes, int n_in,
                              void* d_out, int out_size, void* d_ws, size_t ws_size,
                              hipStream_t stream) {
    const float* pred = (const float*)d_in[0];
    const float* targ = (const float*)d_in[1];
    const float* kern = (const float*)d_in[2];
    float* out = (float*)d_out;

    char* ws = (char*)d_ws;
    double* accum = (double*)ws;             // 80 doubles (5 scales * 8 slots * 2)
    size_t off = 1024;
    float* p1 = (float*)(ws + off); off += (size_t)NP * 256 * 256 * 4;
    float* t1 = (float*)(ws + off); off += (size_t)NP * 256 * 256 * 4;
    float* p2 = (float*)(ws + off); off += (size_t)NP * 128 * 128 * 4;
    float* t2 = (float*)(ws + off); off += (size_t)NP * 128 * 128 * 4;
    float* p3 = (float*)(ws + off); off += (size_t)NP * 64 * 64 * 4;
    float* t3 = (float*)(ws + off); off += (size_t)NP * 64 * 64 * 4;
    float* p4 = (float*)(ws + off); off += (size_t)NP * 32 * 32 * 4;
    float* t4 = (float*)(ws + off); off += (size_t)NP * 32 * 32 * 4;

    hipMemsetAsync(accum, 0, 640, stream);
    k_main<<<3072, 256, 0, stream>>>(pred, targ, p1, t1, p2, t2, p3, t3, p4, t4, kern, accum);
    k_ssim_rest<<<510, 256, 0, stream>>>(p1, t1, p2, t2, p3, t3, p4, t4, kern, accum);
    k_final<<<1, 1, 0, stream>>>(accum, out);
}

// Round 13
// 218.793 us; speedup vs baseline: 1.3557x; 1.0847x over previous
//
#include <hip/hip_runtime.h>
#include <math.h>

#define NP 48   // 16 batch * 3 channels

typedef float v2f __attribute__((ext_vector_type(2)));

__device__ __forceinline__ float uniform_f(float v) {
    int i = __builtin_amdgcn_readfirstlane(__builtin_bit_cast(int, v));
    return __builtin_bit_cast(float, i);
}

// ---------------- sliding-window SSIM core with 1-step register prefetch ----------------
// Loads for row rr+1 are issued UNCONDITIONALLY (clamped row address) before the
// compute of row rr, so they are never fenced behind the row-guard branch.
__device__ __forceinline__ void ssim_scale(
        const float* __restrict__ P, const float* __restrict__ T,
        int H, int sh, int lb, int scale, int slotsel, int tid,
        const float* __restrict__ k2d, double* __restrict__ accum)
{
    // normalized 1D gaussian from center row of 2D kernel, pinned to SGPRs
    float w[11];
    {
        float s = 0.f;
#pragma unroll
        for (int i = 0; i < 11; ++i) s += k2d[55 + i];
        float inv = 1.0f / s;
#pragma unroll
        for (int i = 0; i < 11; ++i) w[i] = uniform_f(k2d[55 + i] * inv);
    }

    int blocksX = (NP << sh) >> 8;          // 48*H / 256
    int bxi = lb % blocksX;
    int by  = lb / blocksX;
    int g   = (bxi << 8) + tid;
    int pl  = g >> sh;
    int x   = g & (H - 1);
    int yb  = by * 32;

    // per-lane clamped window base + edge-zeroed weights (unified load path)
    int bcl = x - 5;
    bcl = bcl < 0 ? 0 : bcl;
    bcl = bcl > H - 11 ? H - 11 : bcl;
    int d = bcl - (x - 5);                  // in [-5, 5]; 0 interior
    float wc[11];
#pragma unroll
    for (int j = 0; j < 11; ++j) {
        int idx = j + d;
        float val = 0.f;
#pragma unroll
        for (int i = 0; i < 11; ++i) val = (idx == i) ? w[i] : val;
        wc[j] = val;
    }

    const float* Pb = P + (size_t)pl * H * H + bcl;   // plane base + per-lane col base
    const float* Tb = T + (size_t)pl * H * H + bcl;

    v2f tap[2][11];                         // raw {p,t} taps, double-buffered
    v2f wmu[11], we[11];
    float wpt[11];
    const float C1 = 1e-4f, C2 = 9e-4f;
    float lsum = 0.f, csum = 0.f;
    int rr = yb - 5;                        // compute row of step 0

    // preload step-0 row (clamped; if rr<0 the compute guard discards it)
    {
        int cr = rr < 0 ? 0 : rr;           // uniform
        const float* rp = Pb + (size_t)cr * H;
        const float* rt = Tb + (size_t)cr * H;
#pragma unroll
        for (int j = 0; j < 11; ++j) tap[0][j] = (v2f){rp[j], rt[j]};
    }

    for (int ch = 0; ch < 2; ++ch) {        // 2 chunks * 22 steps = 44 >= 42 live steps
#pragma unroll
        for (int ph = 0; ph < 22; ++ph) {
            const int cb = ph & 1;          // compile-time buffer parity (22 even)
            const int sl = ph % 11;         // compile-time window slot (22 % 11 == 0)

            // ---- branchless prefetch of row rr+1 into tap[cb^1] ----
            {
                int nr = rr + 1;
                nr = nr < 0 ? 0 : nr;
                nr = nr > H - 1 ? H - 1 : nr;   // uniform clamp -> always-valid address
                const float* rp = Pb + (size_t)nr * H;
                const float* rt = Tb + (size_t)nr * H;
#pragma unroll
                for (int j = 0; j < 11; ++j) tap[cb ^ 1][j] = (v2f){rp[j], rt[j]};
            }

            bool live = rr < yb + 37;       // global step < 42 (uniform)
            // ---- h-blur from tap[cb] (row rr) ----
            v2f a_mu = (v2f){0.f, 0.f};
            v2f a_e  = (v2f){0.f, 0.f};
            v2f a_pt = (v2f){0.f, 0.f};
            if (live && rr >= 0 && rr < H) {   // uniform; taps already in registers
#pragma unroll
                for (int j = 0; j < 11; ++j) {
                    v2f pt2 = tap[cb][j];
                    v2f wv  = (v2f){wc[j], wc[j]};
                    v2f wp2 = wv * pt2;
                    v2f ptr2 = (v2f){pt2.y, pt2.x};
                    a_mu += wp2;
                    a_e  += wp2 * pt2;
                    a_pt += wp2 * ptr2;        // halves: wp*t , wt*p
                }
            }
            wmu[sl] = a_mu; we[sl] = a_e;
            wpt[sl] = a_pt.x + a_pt.y;         // = 2*sum(w p t)

            if (live && rr >= yb + 5) {        // emit output row rr-5
                v2f mu2 = (v2f){0.f, 0.f};
                v2f e2  = (v2f){0.f, 0.f};
                float ept = 0.f;
#pragma unroll
                for (int i = 0; i < 11; ++i) {
                    const int ss = (sl + 1 + i) % 11;   // compile-time
                    v2f wi = (v2f){w[i], w[i]};         // SGPR broadcast
                    mu2 += wi * wmu[ss];
                    e2  += wi * we[ss];
                    ept += w[i] * wpt[ss];
                }
                float m11 = mu2.x * mu2.x, m22 = mu2.y * mu2.y, m12 = mu2.x * mu2.y;
                float s1  = fmaxf(e2.x - m11, 0.f);
                float s2  = fmaxf(e2.y - m22, 0.f);
                float s12 = 0.5f * ept - m12;
                lsum += (2.f * m12 + C1) * __builtin_amdgcn_rcpf(m11 + m22 + C1);
                csum += (2.f * s12 + C2) * __builtin_amdgcn_rcpf(s1 + s2 + C2);
            }
            rr++;
        }
    }

    // wave shuffle reduce then cross-wave via LDS
#pragma unroll
    for (int o = 32; o > 0; o >>= 1) {
        lsum += __shfl_down(lsum, o, 64);
        csum += __shfl_down(csum, o, 64);
    }
    __shared__ float red[8];
    int wv = tid >> 6;
    if ((tid & 63) == 0) { red[2 * wv] = lsum; red[2 * wv + 1] = csum; }
    __syncthreads();
    if (tid == 0) {
        int slot = (scale * 8 + slotsel) * 2;
        atomicAdd(&accum[slot],     (double)(red[0] + red[2] + red[4] + red[6]));
        atomicAdd(&accum[slot + 1], (double)(red[1] + red[3] + red[5] + red[7]));
    }
}

// ---------------- kernel A: pool blocks [0,1536) || ssim scale-0 blocks [1536,3072) ----------------
__global__ __launch_bounds__(256) void k_main(
        const float* __restrict__ pred, const float* __restrict__ targ,
        float* __restrict__ p1, float* __restrict__ t1,
        float* __restrict__ p2, float* __restrict__ t2,
        float* __restrict__ p3, float* __restrict__ t3,
        float* __restrict__ p4, float* __restrict__ t4,
        const float* __restrict__ k2d, double* __restrict__ accum) {
    int b   = blockIdx.x;
    int tid = threadIdx.x;
    if (b >= 1536) {
        ssim_scale(pred, targ, 512, 9, b - 1536, 0, b & 7, tid, k2d, accum);
        return;
    }
    // ---- pool path: 64x64 s1 tile; all scales from s0 (mean of means) ----
    int pi   = b >> 4;          // 0..95 plane-image
    int tile = b & 15;          // 4x4 tiles over the 256x256 s1 plane
    int pls  = pi < 48 ? pi : pi - 48;
    const float* src = (pi < 48 ? pred : targ) + (size_t)pls * 512 * 512;
    float* d1 = (pi < 48 ? p1 : t1) + (size_t)pls * 256 * 256;
    float* d2 = (pi < 48 ? p2 : t2) + (size_t)pls * 128 * 128;
    float* d3 = (pi < 48 ? p3 : t3) + (size_t)pls * 64 * 64;
    float* d4 = (pi < 48 ? p4 : t4) + (size_t)pls * 32 * 32;
    int tY = tile >> 2, tX = tile & 3;
    int ty = tid >> 4, tx = tid & 15;
    int gy0 = tY * 128 + ty * 8, gx0 = tX * 128 + tx * 8;

    float s1v[4][4];
#pragma unroll
    for (int i = 0; i < 4; ++i) {
        const float* r0 = src + (size_t)(gy0 + 2 * i) * 512 + gx0;
        const float* r1 = r0 + 512;
        float4 a0 = *(const float4*)r0, a1 = *(const float4*)(r0 + 4);
        float4 b0 = *(const float4*)r1, b1 = *(const float4*)(r1 + 4);
        s1v[i][0] = 0.25f * ((a0.x + a0.y) + (b0.x + b0.y));
        s1v[i][1] = 0.25f * ((a0.z + a0.w) + (b0.z + b0.w));
        s1v[i][2] = 0.25f * ((a1.x + a1.y) + (b1.x + b1.y));
        s1v[i][3] = 0.25f * ((a1.z + a1.w) + (b1.z + b1.w));
        *(float4*)(d1 + (size_t)(tY * 64 + ty * 4 + i) * 256 + tX * 64 + tx * 4) =
            *(float4*)s1v[i];
    }
    float s2v[2][2];
#pragma unroll
    for (int i = 0; i < 2; ++i) {
#pragma unroll
        for (int j = 0; j < 2; ++j)
            s2v[i][j] = 0.25f * ((s1v[2*i][2*j] + s1v[2*i][2*j+1]) +
                                 (s1v[2*i+1][2*j] + s1v[2*i+1][2*j+1]));
        *(float2*)(d2 + (size_t)(tY * 32 + ty * 2 + i) * 128 + tX * 32 + tx * 2) =
            *(float2*)s2v[i];
    }
    float s3 = 0.25f * ((s2v[0][0] + s2v[0][1]) + (s2v[1][0] + s2v[1][1]));
    d3[(size_t)(tY * 16 + ty) * 64 + tX * 16 + tx] = s3;
    float v1 = s3 + __shfl_xor(s3, 1, 64);
    float v2 = v1 + __shfl_xor(v1, 16, 64);
    if ((ty & 1) == 0 && (tx & 1) == 0)
        d4[(size_t)(tY * 8 + (ty >> 1)) * 32 + tX * 8 + (tx >> 1)] = 0.25f * v2;
}

// ---------------- kernel B: ssim scales 1-4 (depend on pools) ----------------
__global__ __launch_bounds__(256) void k_ssim_rest(
        const float* __restrict__ p1, const float* __restrict__ t1,
        const float* __restrict__ p2, const float* __restrict__ t2,
        const float* __restrict__ p3, const float* __restrict__ t3,
        const float* __restrict__ p4, const float* __restrict__ t4,
        const float* __restrict__ k2d, double* __restrict__ accum) {
    int b   = blockIdx.x;
    int tid = threadIdx.x;
    if (b < 384)      ssim_scale(p1, t1, 256, 8, b,       1, b & 7, tid, k2d, accum);
    else if (b < 480) ssim_scale(p2, t2, 128, 7, b - 384, 2, b & 7, tid, k2d, accum);
    else if (b < 504) ssim_scale(p3, t3, 64,  6, b - 480, 3, b & 7, tid, k2d, accum);
    else              ssim_scale(p4, t4, 32,  5, b - 504, 4, b & 7, tid, k2d, accum);
}

// ---------------- finalize: weighted power product ----------------
__global__ void k_final(const double* __restrict__ accum, float* __restrict__ out) {
    if (threadIdx.x != 0 || blockIdx.x != 0) return;
    const float wts[5] = {0.0448f, 0.2856f, 0.3001f, 0.2363f, 0.1333f};
    float ms = 1.0f;
    int Hs = 512;
    for (int s = 0; s < 5; ++s) {
        double lt = 0.0, ct = 0.0;
        for (int k = 0; k < 8; ++k) {
            lt += accum[(s * 8 + k) * 2];
            ct += accum[(s * 8 + k) * 2 + 1];
        }
        float N  = 48.0f * (float)Hs * (float)Hs;
        float l  = (float)lt / N;
        float cs = fmaxf((float)ct / N, 1e-8f);
        if (s == 4) {
            l = fmaxf(l, 1e-8f);
            ms *= powf(l, wts[s]) * powf(cs, wts[s]);
        } else {
            ms *= powf(cs, wts[s]);
        }
        Hs >>= 1;
    }
    out[0] = ms;
}

extern "C" void kernel_launch(void* const* d_in, const int* in_sizes, int n_in,
                              void* d_out, int out_size, void* d_ws, size_t ws_size,
                              hipStream_t stream) {
    const float* pred = (const float*)d_in[0];
    const float* targ = (const float*)d_in[1];
    const float* kern = (const float*)d_in[2];
    float* out = (float*)d_out;

    char* ws = (char*)d_ws;
    double* accum = (double*)ws;             // 80 doubles (5 scales * 8 slots * 2)
    size_t off = 1024;
    float* p1 = (float*)(ws + off); off += (size_t)NP * 256 * 256 * 4;
    float* t1 = (float*)(ws + off); off += (size_t)NP * 256 * 256 * 4;
    float* p2 = (float*)(ws + off); off += (size_t)NP * 128 * 128 * 4;
    float* t2 = (float*)(ws + off); off += (size_t)NP * 128 * 128 * 4;
    float* p3 = (float*)(ws + off); off += (size_t)NP * 64 * 64 * 4;
    float* t3 = (float*)(ws + off); off += (size_t)NP * 64 * 64 * 4;
    float* p4 = (float*)(ws + off); off += (size_t)NP * 32 * 32 * 4;
    float* t4 = (float*)(ws + off); off += (size_t)NP * 32 * 32 * 4;

    hipMemsetAsync(accum, 0, 640, stream);
    k_main<<<3072, 256, 0, stream>>>(pred, targ, p1, t1, p2, t2, p3, t3, p4, t4, kern, accum);
    k_ssim_rest<<<510, 256, 0, stream>>>(p1, t1, p2, t2, p3, t3, p4, t4, kern, accum);
    k_final<<<1, 1, 0, stream>>>(accum, out);
}